// Round 1
// 6254.811 us; speedup vs baseline: 1.8684x; 1.8684x over previous
//
#include <hip/hip_runtime.h>
#include <stdint.h>

// LSTM: T=256 steps, B=64, E=512, H=1024, V=10000
// Strategy:
//   K0  prep: transpose/cast weights to bf16 [N,K] layouts, gather x-embeddings,
//       pack gate bias, zero barrier counters.
//   K1  GEMM (bf16 MFMA): xg[16384,4096] = xemb[16384,512] @ WgX^T + b_g  (x-part of
//       gates hoisted out of the time loop).
//   K2  persistent recurrence: 256 blocks = 4 batch-groups x 64 hid-blocks.
//       Each block holds its Wr slice (64 gate cols x 1024 K, bf16) in LDS,
//       does one MFMA 16x16x32 chain per wave per step (wave==gate), exchanges
//       gates via LDS, keeps c in fp32 registers, per-group device-scope barrier.
//       Barrier v2: h communicated via relaxed agent (write-through sc1) stores +
//       vmcnt(0); relaxed atomics; ONE acquire fence (buffer_inv) per step.
//       (v1 used __threadfence [full L2 writeback] + ACQUIRE spin [L2 invalidate
//        per poll] -> ~32 us/step of pure cache-maintenance stall.)
//   K3  GEMM (bf16 MFMA): y[16384,10000] = all_h[16384,1024] @ Wout^T + b_out.

#define T_STEPS 256
#define BATCH   64
#define EDIM    512
#define HDIM    1024
#define VDIM    10000
#define G4H     4096
#define VPAD    10048   // VDIM padded to multiple of 64 (pad rows zero-filled)

typedef __bf16 bf16x8 __attribute__((ext_vector_type(8)));
typedef float  f32x4  __attribute__((ext_vector_type(4)));

__device__ __forceinline__ unsigned short f2bf(float f) {
  union { float f; unsigned int u; } v; v.f = f;
  unsigned int r = v.u + 0x7fffu + ((v.u >> 16) & 1u);  // round-to-nearest-even
  return (unsigned short)(r >> 16);
}
__device__ __forceinline__ float bf2f(unsigned short u) {
  union { unsigned int u; float f; } v; v.u = ((unsigned int)u) << 16;
  return v.f;
}
__device__ __forceinline__ bf16x8 ldfrag(const unsigned short* p) {
  uint4 u = *(const uint4*)p;   // 16B aligned by construction
  return __builtin_bit_cast(bf16x8, u);
}
__device__ __forceinline__ float sigm(float x) { return 1.f / (1.f + __expf(-x)); }
__device__ __forceinline__ float tanh_f(float x) { return 2.f / (1.f + __expf(-2.f * x)) - 1.f; }

// ---------------------------------------------------------------- prep kernels

__global__ void k_zero_ctr(unsigned int* ctr) { ctr[threadIdx.x] = 0u; }

// grid = T*B blocks, 128 threads: xemb[row][0..511] = bf16(emb[x[row]][:])
__global__ void k_pack_xemb(const int* __restrict__ x, const float* __restrict__ emb,
                            unsigned short* __restrict__ xemb) {
  const int row = blockIdx.x;
  const int v = x[row];
  const float4* src = (const float4*)(emb + (long)v * EDIM);
  float4 f = src[threadIdx.x];
  ushort4 o; o.x = f2bf(f.x); o.y = f2bf(f.y); o.z = f2bf(f.z); o.w = f2bf(f.w);
  ((ushort4*)(xemb + (long)row * EDIM))[threadIdx.x] = o;
}

// out[c][r] = bf16(in[r][c]); out has Cp rows (rows >= C zero-filled).
// block (32,8); grid ((Cp+31)/32, R/32). R must be a multiple of 32 (it is).
__global__ void k_transpose_cast(const float* __restrict__ in, int R, int C,
                                 unsigned short* __restrict__ out, int Cp) {
  __shared__ float tile[32][33];
  int c0 = blockIdx.x * 32, r0 = blockIdx.y * 32;
  for (int i = 0; i < 32; i += 8) {
    int r = r0 + threadIdx.y + i, c = c0 + threadIdx.x;
    tile[threadIdx.y + i][threadIdx.x] = (r < R && c < C) ? in[(long)r * C + c] : 0.f;
  }
  __syncthreads();
  for (int i = 0; i < 32; i += 8) {
    int oc = c0 + threadIdx.y + i;   // output row (= input col)
    int orr = r0 + threadIdx.x;      // output col (= input row)
    if (oc < Cp) out[(long)oc * R + orr] = f2bf(tile[threadIdx.x][threadIdx.y + i]);
  }
}

__global__ void k_pack_bias(const float* __restrict__ bf_, const float* __restrict__ bi,
                            const float* __restrict__ bc, const float* __restrict__ bo,
                            float* __restrict__ bias_g) {
  int j = blockIdx.x * 256 + threadIdx.x;
  int q = j >> 10, jj = j & 1023;
  const float* src = (q == 0) ? bf_ : (q == 1) ? bi : (q == 2) ? bc : bo;
  bias_g[j] = src[jj];
}

// ---------------------------------------------------------------- bf16 GEMM
// C[M,N] = A[M,K](bf16,row-major) @ BT[N,K](bf16,row-major)^T + bias[N]
// block = 256 threads (4 waves, 2x2 wave grid), 64x64 tile, direct-global frags.
// MFMA 16x16x32 bf16 layouts (HW-verified, learn_hip m89/m91):
//   A frag: m = lane&15, k = (lane>>4)*8 + j   (8 contiguous bf16 -> 16B load)
//   B frag: n = lane&15, k = (lane>>4)*8 + j   (from BT row-major -> 16B load)
//   D:      col = lane&15, row = (lane>>4)*4 + reg
template <int OUT_BF16>
__global__ __launch_bounds__(256) void gemm_bt(
    const unsigned short* __restrict__ A, const unsigned short* __restrict__ BT,
    const float* __restrict__ bias, void* __restrict__ Cout,
    int K, int ldC, int Nvalid) {
  const int wave = threadIdx.x >> 6;
  const int lane = threadIdx.x & 63;
  const int m16 = lane & 15;
  const int quad = lane >> 4;
  const long m_base = (long)blockIdx.x * 64 + (wave & 1) * 32;
  const long n_base = (long)blockIdx.y * 64 + (wave >> 1) * 32;
  const unsigned short* a0p = A + (m_base + m16) * K + quad * 8;
  const unsigned short* a1p = a0p + 16 * K;
  const unsigned short* b0p = BT + (n_base + m16) * K + quad * 8;
  const unsigned short* b1p = b0p + 16 * K;
  f32x4 acc00 = {0.f, 0.f, 0.f, 0.f};
  f32x4 acc01 = acc00, acc10 = acc00, acc11 = acc00;
  for (int k0 = 0; k0 < K; k0 += 32) {
    bf16x8 a0 = ldfrag(a0p + k0);
    bf16x8 a1 = ldfrag(a1p + k0);
    bf16x8 b0 = ldfrag(b0p + k0);
    bf16x8 b1 = ldfrag(b1p + k0);
    acc00 = __builtin_amdgcn_mfma_f32_16x16x32_bf16(a0, b0, acc00, 0, 0, 0);
    acc01 = __builtin_amdgcn_mfma_f32_16x16x32_bf16(a0, b1, acc01, 0, 0, 0);
    acc10 = __builtin_amdgcn_mfma_f32_16x16x32_bf16(a1, b0, acc10, 0, 0, 0);
    acc11 = __builtin_amdgcn_mfma_f32_16x16x32_bf16(a1, b1, acc11, 0, 0, 0);
  }
  f32x4 accs[2][2] = {{acc00, acc01}, {acc10, acc11}};
  for (int i = 0; i < 2; ++i)
    for (int j = 0; j < 2; ++j)
      for (int r = 0; r < 4; ++r) {
        long row = m_base + i * 16 + quad * 4 + r;
        long col = n_base + j * 16 + m16;
        if (col < Nvalid) {
          float v = accs[i][j][r] + bias[col];
          if (OUT_BF16)
            ((unsigned short*)Cout)[row * ldC + col] = f2bf(v);
          else
            ((float*)Cout)[row * ldC + col] = v;
        }
      }
}

// ---------------------------------------------------------------- recurrence

// Minimal-coherence group barrier (64 blocks).
// Contract: all cross-block-communicated data (hbf) was written with relaxed
// AGENT-scope (write-through) stores. s_waitcnt vmcnt(0) makes those globally
// visible; the arrival/spin atomics are RELAXED (no buffer_wbl2, no per-poll
// buffer_inv); ONE acquire fence (buffer_inv) after the barrier makes the
// subsequent plain cached loads of hbf see fresh data.
__device__ __forceinline__ void stream_barrier(unsigned int* c, unsigned int target) {
  asm volatile("s_waitcnt vmcnt(0)" ::: "memory");
  __syncthreads();
  if (threadIdx.x == 0) {
    __hip_atomic_fetch_add(c, 1u, __ATOMIC_RELAXED, __HIP_MEMORY_SCOPE_AGENT);
    while (__hip_atomic_load(c, __ATOMIC_RELAXED, __HIP_MEMORY_SCOPE_AGENT) < target)
      __builtin_amdgcn_s_sleep(1);
  }
  __syncthreads();
  __builtin_amdgcn_fence(__ATOMIC_ACQUIRE, "agent");
}

// 256 blocks: blockIdx = g*64 + p ; g = batch group (16 batches), p = hid block
// (16 hids). Block owns gate cols {q*1024 + p*16 .. +15 | q=0..3} (64 cols).
// Wave w computes gate w's 16x16 (batch x hid) tile via MFMA over K=1024.
// LDS: Wr slice 64 x 1024 bf16, row-padded +8 bf16 -> 2-way bank alias (free).
__global__ __launch_bounds__(256, 1) void lstm_rec(
    const unsigned short* __restrict__ WrT,  // [4096][1024] bf16
    const unsigned short* __restrict__ xg,   // [T][B][4096] bf16
    const float* __restrict__ h_in, const float* __restrict__ c_in,
    unsigned short* __restrict__ hbf,        // [T+1][B][1024] bf16
    float* __restrict__ allh, float* __restrict__ allc,
    unsigned int* __restrict__ ctr) {
  __shared__ unsigned short ldsW[64][1032];  // 132096 B
  __shared__ float gbuf[4][16][17];          // 4352 B
  const int tid = threadIdx.x;
  const int g = blockIdx.x >> 6;
  const int p = blockIdx.x & 63;
  const int b0 = g * 16;
  const int hid0 = p * 16;

  // stage Wr slice: local col c -> global row q*1024 + hid0 + (c&15)
  for (int idx = tid; idx < 64 * 128; idx += 256) {
    int c = idx >> 7, chunk = idx & 127;
    int j = ((c >> 4) << 10) + hid0 + (c & 15);
    *(uint4*)&ldsW[c][chunk * 8] = *(const uint4*)&WrT[(long)j * HDIM + chunk * 8];
  }

  const int lb = tid >> 4, lh = tid & 15;
  const int b = b0 + lb, hid = hid0 + lh;
  float c_reg = c_in[b * HDIM + hid];
  // h0 -> hbf via relaxed agent store (pair-packed to 4B; even lanes store).
  {
    unsigned int me = f2bf(h_in[b * HDIM + hid]);
    unsigned int pr = (unsigned int)__shfl_down((int)me, 1);
    if (!(tid & 1))
      __hip_atomic_store((unsigned int*)(hbf + (long)b * HDIM + hid),
                         me | (pr << 16), __ATOMIC_RELAXED, __HIP_MEMORY_SCOPE_AGENT);
  }

  unsigned int* myctr = ctr + g * 64;
  const int wave = tid >> 6, lane = tid & 63, m16 = lane & 15, quad = lane >> 4;

  stream_barrier(myctr, 64u);  // h0 visible group-wide; also covers LDS staging

  for (int t = 0; t < T_STEPS; ++t) {
    const unsigned short* hrow =
        hbf + (long)t * (BATCH * HDIM) + (b0 + m16) * HDIM + quad * 8;
    const unsigned short* wrow = &ldsW[wave * 16 + m16][quad * 8];
    f32x4 acc = {0.f, 0.f, 0.f, 0.f};
    for (int k0 = 0; k0 < HDIM; k0 += 32) {
      bf16x8 af = ldfrag(hrow + k0);
      bf16x8 bf_ = ldfrag(wrow + k0);
      acc = __builtin_amdgcn_mfma_f32_16x16x32_bf16(af, bf_, acc, 0, 0, 0);
    }
    // D tile: row(batch-local) = quad*4+r, col(hid-local) = m16. Add xg, share.
    const long xbase = ((long)t * BATCH + b0) * G4H + (wave << 10) + hid0 + m16;
    for (int r = 0; r < 4; ++r) {
      int rb = quad * 4 + r;
      gbuf[wave][rb][m16] = acc[r] + bf2f(xg[xbase + (long)rb * G4H]);
    }
    __syncthreads();
    float F = sigm(gbuf[0][lb][lh]);
    float I = sigm(gbuf[1][lb][lh]);
    float Cd = tanh_f(gbuf[2][lb][lh]);
    float O = sigm(gbuf[3][lb][lh]);
    c_reg = F * c_reg + I * Cd;
    float hn = O * tanh_f(c_reg);
    // h_{t+1} -> hbf via relaxed agent store (write-through; issued first so the
    // round trip overlaps the plain allh/allc stores).
    {
      unsigned int me = f2bf(hn);
      unsigned int pr = (unsigned int)__shfl_down((int)me, 1);
      if (!(tid & 1))
        __hip_atomic_store(
            (unsigned int*)(hbf + (long)(t + 1) * (BATCH * HDIM) + b * HDIM + hid),
            me | (pr << 16), __ATOMIC_RELAXED, __HIP_MEMORY_SCOPE_AGENT);
    }
    long oidx = ((long)t * BATCH + b) * HDIM + hid;
    allh[oidx] = hn;
    allc[oidx] = c_reg;
    stream_barrier(myctr, 64u * (unsigned)(t + 2));
  }
}

// ---------------------------------------------------------------- launch

extern "C" void kernel_launch(void* const* d_in, const int* in_sizes, int n_in,
                              void* d_out, int out_size, void* d_ws, size_t ws_size,
                              hipStream_t stream) {
  const int*   x     = (const int*)d_in[0];
  const float* h_in  = (const float*)d_in[1];
  const float* c_in  = (const float*)d_in[2];
  const float* emb   = (const float*)d_in[3];
  const float* Wf    = (const float*)d_in[4];
  const float* bfb   = (const float*)d_in[5];
  const float* Wi    = (const float*)d_in[6];
  const float* bib   = (const float*)d_in[7];
  const float* Wc    = (const float*)d_in[8];
  const float* bcb   = (const float*)d_in[9];
  const float* Wo    = (const float*)d_in[10];
  const float* bob   = (const float*)d_in[11];
  const float* Wout  = (const float*)d_in[12];
  const float* boutb = (const float*)d_in[13];

  float* allh = (float*)d_out;
  float* allc = allh + (size_t)T_STEPS * BATCH * HDIM;
  float* ally = allc + (size_t)T_STEPS * BATCH * HDIM;

  // Workspace layout. Structures K3 still needs (WoutT, hbf, bias, ctr) must
  // live in d_ws. Structures dead before K3 (WrT, WgXT, xemb, xg) fall back to
  // the y-region of d_out (655 MB, written only by K3) if d_ws is small.
  char* ws = (char*)d_ws;
  size_t off = 0;
  char* yscr = (char*)ally;
  size_t yoff = 0;
  const bool ws_big = ws_size >= (size_t)240 * 1024 * 1024;
  auto alloc = [&](size_t bytes, bool essential) -> void* {
    if (essential || ws_big) {
      void* p = ws + off;
      off = (off + bytes + 255) & ~(size_t)255;
      return p;
    }
    void* p = yscr + yoff;
    yoff = (yoff + bytes + 255) & ~(size_t)255;
    return p;
  };
  unsigned short* WoutT = (unsigned short*)alloc((size_t)VPAD * HDIM * 2, true);
  unsigned short* hbf   = (unsigned short*)alloc((size_t)(T_STEPS + 1) * BATCH * HDIM * 2, true);
  float*          biasg = (float*)alloc((size_t)G4H * 4, true);
  unsigned int*   ctr   = (unsigned int*)alloc(256 * 4, true);
  unsigned short* WrT   = (unsigned short*)alloc((size_t)G4H * HDIM * 2, false);
  unsigned short* WgXT  = (unsigned short*)alloc((size_t)G4H * EDIM * 2, false);
  unsigned short* xemb  = (unsigned short*)alloc((size_t)T_STEPS * BATCH * EDIM * 2, false);
  unsigned short* xg    = (unsigned short*)alloc((size_t)T_STEPS * BATCH * G4H * 2, false);

  k_zero_ctr<<<1, 256, 0, stream>>>(ctr);
  k_pack_xemb<<<T_STEPS * BATCH, 128, 0, stream>>>(x, emb, xemb);
  const float* Wg[4] = {Wf, Wi, Wc, Wo};
  for (int q = 0; q < 4; ++q) {
    // h-part (rows 0..1023) -> WrT section [1024 x 1024]
    k_transpose_cast<<<dim3(32, 32), dim3(32, 8), 0, stream>>>(
        Wg[q], HDIM, HDIM, WrT + (size_t)q * HDIM * HDIM, HDIM);
    // x-part (rows 1024..1535) -> WgXT section [1024 x 512]
    k_transpose_cast<<<dim3(32, 16), dim3(32, 8), 0, stream>>>(
        Wg[q] + (size_t)HDIM * HDIM, EDIM, HDIM, WgXT + (size_t)q * HDIM * EDIM, HDIM);
  }
  k_transpose_cast<<<dim3(VPAD / 32, HDIM / 32), dim3(32, 8), 0, stream>>>(
      Wout, HDIM, VDIM, WoutT, VPAD);
  k_pack_bias<<<G4H / 256, 256, 0, stream>>>(bfb, bib, bcb, bob, biasg);

  // K1: xg[16384,4096] bf16 = xemb @ WgXT^T + bias_g
  gemm_bt<1><<<dim3((T_STEPS * BATCH) / 64, G4H / 64), 256, 0, stream>>>(
      xemb, WgXT, biasg, xg, EDIM, G4H, G4H);
  // K2: recurrence
  lstm_rec<<<256, 256, 0, stream>>>(WrT, xg, h_in, c_in, hbf, allh, allc, ctr);
  // K3: y[16384,10000] fp32 = all_h(bf16) @ WoutT^T + b_out
  gemm_bt<0><<<dim3((T_STEPS * BATCH) / 64, VPAD / 64), 256, 0, stream>>>(
      hbf + (size_t)BATCH * HDIM, WoutT, boutb, ally, HDIM, VDIM, VDIM);
}